// Round 15
// baseline (367.281 us; speedup 1.0000x reference)
//
#include <hip/hip_runtime.h>

namespace {
constexpr int T = 512;
constexpr int BATCH = 512;
constexpr int D = 32;
constexpr int H = 64;
constexpr int G3 = 192;
}

typedef float v2f __attribute__((ext_vector_type(2)));

__device__ __forceinline__ float rcpf(float x) { return __builtin_amdgcn_rcpf(x); }
__device__ __forceinline__ float sigm(float x) { return rcpf(1.0f + __expf(-x)); }
__device__ __forceinline__ float tanh_fast(float x) {
    return 1.0f - 2.0f * rcpf(__expf(2.0f * x) + 1.0f);
}
__device__ __forceinline__ void pk2(v2f& acc, v2f w, v2f v) {
    asm("v_pk_fma_f32 %0, %1, %2, %0" : "+v"(acc) : "v"(w), "v"(v));
}

// ---- phase 1: xp[b][t][g] = sum_d x[b][t][d] * w_ih_f[g][d] + b_ih_f[g] ----
__global__ __launch_bounds__(G3) void xproj_kernel(
    const float* __restrict__ x, const float* __restrict__ w_ih_f,
    const float* __restrict__ b_ih_f, float* __restrict__ xp)
{
    const int bidx = blockIdx.x;      // 0..2047
    const int b = bidx >> 2;          // batch row
    const int c = bidx & 3;           // t-chunk of 128
    const int tid = threadIdx.x;      // 0..191 = gate-output g

    __shared__ float4 xs[128 * (D / 4)];   // 16 KB chunk of x

    {
        const float4* xg = reinterpret_cast<const float4*>(
            x + ((size_t)b * T + (size_t)c * 128) * D);
        for (int i = tid; i < 128 * (D / 4); i += G3) xs[i] = xg[i];
    }
    v2f w[16];
    {
        const v2f* wp = reinterpret_cast<const v2f*>(w_ih_f + (size_t)tid * D);
        #pragma unroll
        for (int m = 0; m < 16; ++m) w[m] = wp[m];
    }
    const float bias = b_ih_f[tid];
    __syncthreads();

    float* xpo = xp + ((size_t)b * T + (size_t)c * 128) * G3 + tid;
    for (int tt = 0; tt < 128; ++tt) {
        const float4* xr = &xs[tt * (D / 4)];
        v2f acc = {0.f, 0.f};
        #pragma unroll
        for (int m = 0; m < D / 4; ++m) {
            float4 xv = xr[m];
            v2f lo = {xv.x, xv.y}, hi = {xv.z, xv.w};
            pk2(acc, w[2 * m], lo);
            pk2(acc, w[2 * m + 1], hi);
        }
        xpo[(size_t)tt * G3] = acc.x + acc.y + bias;   // coalesced across g
    }
}

// -- phase 2: 1 wave/row, lane j owns h_j, full-K fp32 in-lane, NO barrier ---
__global__ __launch_bounds__(64, 1) void gru_rec_kernel(
    const float* __restrict__ x, const float* __restrict__ xp,
    const float* __restrict__ w_hh_f,
    const float* __restrict__ b_hh_f,
    const float* __restrict__ w_ih_b, const float* __restrict__ b_ih_b,
    const float* __restrict__ b_hh_b,
    const float* __restrict__ fc1_w, const float* __restrict__ fc1_b,
    const float* __restrict__ fc2_w, const float* __restrict__ fc2_b,
    float* __restrict__ out)
{
    const int b = blockIdx.x;
    const int j = threadIdx.x;   // 0..63: lane j owns h-index j, all 3 gates

    // ~57 KB pad: keeps the allocator's occupancy model at 2 blocks/CU, the
    // config that granted 204 VGPR in R4 (64-thr + 66KB LDS). Without big LDS
    // the grant collapses to 64-132 and weights get rematerialized in-loop.
    __shared__ float4 pad_lds[3584];
    __shared__ __align__(16) float h32[H];     // h broadcast buffer (fp32)
    __shared__ float last_lds[2 * H];

    // data-dependent never-true touch so pad_lds can't be DCE'd
    if (x[0] > 3.0e38f) {
        pad_lds[j] = make_float4(0.f, 0.f, 0.f, 0.f);
        out[b] = pad_lds[(j + 7) & 3583].x;
    }

    // ---- W_hh rows j, H+j, 2H+j in fp32 registers (96 v2f = 192 VGPR) ----
    v2f wr[32], wz[32], wn[32];
    {
        const v2f* pr = reinterpret_cast<const v2f*>(w_hh_f + (size_t)j * H);
        const v2f* pz = reinterpret_cast<const v2f*>(w_hh_f + (size_t)(H + j) * H);
        const v2f* pn = reinterpret_cast<const v2f*>(w_hh_f + (size_t)(2 * H + j) * H);
        #pragma unroll
        for (int m = 0; m < 32; ++m) { wr[m] = pr[m]; wz[m] = pz[m]; wn[m] = pn[m]; }
    }
    // b_ih is folded into xp (phase 1); only b_hh remains here
    const float pre_r  = b_hh_f[j];
    const float pre_z  = b_hh_f[H + j];
    const float pre_nh = b_hh_f[2 * H + j];

    h32[j] = 0.0f;   // same-wave in-order DS pipe: visible to reads below

    const float* xpt = xp + (size_t)b * T * G3 + j;
    // depth-2 xp prefetch (t=0, t=1); each slot reloaded 2 steps ahead
    float ar = xpt[0],   az = xpt[64],       an = xpt[128];
    float br = xpt[G3],  bz = xpt[G3 + 64],  bn = xpt[G3 + 128];

    float hold = 0.0f;

    #define GRU_STEP(XR, XZ, XN, TNEXT)                                        \
    {                                                                          \
        v2f hh[32];                                                            \
        {                                                                      \
            const v2f* hp = reinterpret_cast<const v2f*>(h32);                 \
            _Pragma("unroll")                                                  \
            for (int m = 0; m < 32; ++m) hh[m] = hp[m];                        \
        }                                                                      \
        v2f r0 = {0.f,0.f}, r1 = {0.f,0.f};                                    \
        v2f z0 = {0.f,0.f}, z1 = {0.f,0.f};                                    \
        v2f n0 = {0.f,0.f}, n1 = {0.f,0.f};                                    \
        _Pragma("unroll")                                                      \
        for (int m = 0; m < 16; ++m) {                                         \
            pk2(r0, wr[2*m], hh[2*m]);   pk2(r1, wr[2*m+1], hh[2*m+1]);        \
            pk2(z0, wz[2*m], hh[2*m]);   pk2(z1, wz[2*m+1], hh[2*m+1]);        \
            pk2(n0, wn[2*m], hh[2*m]);   pk2(n1, wn[2*m+1], hh[2*m+1]);        \
        }                                                                      \
        const float cr = XR, cz = XZ, cn = XN;                                 \
        { /* reload this slot for two steps ahead (rides vmcnt queue) */       \
            const float* p = xpt + (size_t)((TNEXT) & (T - 1)) * G3;           \
            XR = p[0]; XZ = p[64]; XN = p[128];                                \
        }                                                                      \
        const v2f rs = r0 + r1, zs = z0 + z1, ns = n0 + n1;                    \
        const float r = sigm(rs.x + rs.y + cr + pre_r);                        \
        const float z = sigm(zs.x + zs.y + cz + pre_z);                        \
        const float n = tanh_fast(cn + r * (ns.x + ns.y + pre_nh));            \
        const float hnew = n + z * (hold - n);                                 \
        hold = hnew;                                                           \
        h32[j] = hnew;  /* in-order DS pipe: next step's reads see it */       \
    }

    for (int t = 0; t < T; t += 2) {
        GRU_STEP(ar, az, an, t + 2)   // even step
        GRU_STEP(br, bz, bn, t + 3)   // odd step
    }
    #undef GRU_STEP

    // ---- epilogue (single wave: same-wave LDS ordering, no barriers) ----
    last_lds[j] = hold;   // forward final state

    {   // backward dir: ONE step from h0=0 on x[b][T-1][:]
        const float* xT = x + ((size_t)b * T + (T - 1)) * D;
        float xr = b_ih_b[j];
        float xz = b_ih_b[H + j];
        float xn = b_ih_b[2 * H + j];
        #pragma unroll
        for (int k = 0; k < D; ++k) {
            const float xv = xT[k];
            xr = fmaf(w_ih_b[(size_t)j * D + k],           xv, xr);
            xz = fmaf(w_ih_b[(size_t)(H + j) * D + k],     xv, xz);
            xn = fmaf(w_ih_b[(size_t)(2 * H + j) * D + k], xv, xn);
        }
        const float r = sigm(xr + b_hh_b[j]);
        const float z = sigm(xz + b_hh_b[H + j]);
        const float n = tanh_fast(xn + r * b_hh_b[2 * H + j]);
        last_lds[H + j] = (1.0f - z) * n;   // z*h0 = 0
    }

    // head: h1 = leaky(fc1_w @ last + fc1_b); out = fc2_w @ h1 + fc2_b
    {
        float acc = fc1_b[j];
        const float* w1 = fc1_w + (size_t)j * (2 * H);
        #pragma unroll 8
        for (int c = 0; c < 2 * H; ++c) acc = fmaf(w1[c], last_lds[c], acc);
        acc = (acc >= 0.0f) ? acc : 0.2f * acc;
        float red = acc * fc2_w[j];
        #pragma unroll
        for (int off = 32; off > 0; off >>= 1)
            red += __shfl_down(red, off);
        if (j == 0) out[b] = red + fc2_b[0];
    }
}

extern "C" void kernel_launch(void* const* d_in, const int* in_sizes, int n_in,
                              void* d_out, int out_size, void* d_ws, size_t ws_size,
                              hipStream_t stream) {
    const float* x      = (const float*)d_in[0];
    const float* w_ih_f = (const float*)d_in[1];
    const float* w_hh_f = (const float*)d_in[2];
    const float* b_ih_f = (const float*)d_in[3];
    const float* b_hh_f = (const float*)d_in[4];
    const float* w_ih_b = (const float*)d_in[5];
    // d_in[6] = w_hh_b unused (backward dir runs one step from h0=0)
    const float* b_ih_b = (const float*)d_in[7];
    const float* b_hh_b = (const float*)d_in[8];
    const float* fc1_w  = (const float*)d_in[9];
    const float* fc1_b  = (const float*)d_in[10];
    const float* fc2_w  = (const float*)d_in[11];
    const float* fc2_b  = (const float*)d_in[12];
    float* out = (float*)d_out;

    // phase 1: xp = x @ W_ih^T + b_ih into d_ws (201 MB, fp32)
    xproj_kernel<<<BATCH * 4, G3, 0, stream>>>(x, w_ih_f, b_ih_f, (float*)d_ws);
    // phase 2: barrier-free recurrence, 1 wave/row, full fp32 W_hh residency
    gru_rec_kernel<<<BATCH, 64, 0, stream>>>(
        x, (const float*)d_ws, w_hh_f, b_hh_f,
        w_ih_b, b_ih_b, b_hh_b, fc1_w, fc1_b, fc2_w, fc2_b, out);
    (void)ws_size; (void)in_sizes; (void)n_in; (void)out_size;
}

// Round 16
// 202.306 us; speedup vs baseline: 1.8155x; 1.8155x over previous
//
#include <hip/hip_runtime.h>

// FINAL KERNEL — measured best (R10: 203.4 us, absmax 0.0).
//
// Structure: one 128-thread block per batch row; 2 waves; lane pair (2j,2j+1)
// owns h-index j with K split in half; all 3 gates computed in-lane (no gate
// exchange); pair-reduce via one DPP quad_perm; single barrier per step.
//
// Session findings (15 rounds):
//  - ~950 cyc/step latency floor across 2/4-wave barrier structures,
//    invariant to instruction count, occupancy, residency, reduce depth.
//  - Barrier-free 1-wave variant (full 228-VGPR residency): 1542 cyc/step —
//    serialized issue costs more than the barrier saves.
//  - Two-phase xp-precompute halves in-loop work: null (barrier/exchange
//    dominates). f16 weights inside the recurrence: fails precision (0.108).
//  - Backward GRU = ONE step from h0=0 (only hs_b[0] is consumed) — w_hh_b
//    unused. Entire backward scan + MLP head fused into the epilogue.

namespace {
constexpr int T = 512;
constexpr int BATCH = 512;
constexpr int D = 32;
constexpr int H = 64;
constexpr int THREADS = 128;  // 2 waves/row; lane pair (2j,2j+1) shares h-index j
}

typedef float v2f __attribute__((ext_vector_type(2)));

__device__ __forceinline__ float rcpf(float x) { return __builtin_amdgcn_rcpf(x); }
__device__ __forceinline__ float sigm(float x) { return rcpf(1.0f + __expf(-x)); }
__device__ __forceinline__ float tanh_fast(float x) {
    // 1 - 2/(e^{2x}+1); saturates via inf/0 at extremes
    return 1.0f - 2.0f * rcpf(__expf(2.0f * x) + 1.0f);
}

// packed fp32 FMA on native 64-bit vector registers: no operand repacking
__device__ __forceinline__ void pk2(v2f& acc, v2f w, v2f v) {
    asm("v_pk_fma_f32 %0, %1, %2, %0" : "+v"(acc) : "v"(w), "v"(v));
}

// sum across a lane pair (l, l^1) — single DPP quad_perm [1,0,3,2], pure VALU
__device__ __forceinline__ float pair_sum(float v) {
    int i = __builtin_bit_cast(int, v);
    float t = __builtin_bit_cast(float,
        __builtin_amdgcn_update_dpp(0, i, 0xB1, 0xF, 0xF, true));
    return v + t;
}

__global__ __launch_bounds__(THREADS, 1) void gru_fused_kernel(
    const float* __restrict__ x,
    const float* __restrict__ w_ih_f, const float* __restrict__ w_hh_f,
    const float* __restrict__ b_ih_f, const float* __restrict__ b_hh_f,
    const float* __restrict__ w_ih_b, const float* __restrict__ b_ih_b,
    const float* __restrict__ b_hh_b,
    const float* __restrict__ fc1_w, const float* __restrict__ fc1_b,
    const float* __restrict__ fc2_w, const float* __restrict__ fc2_b,
    float* __restrict__ out)
{
    const int b   = blockIdx.x;   // batch row
    const int tid = threadIdx.x;
    const int j   = tid >> 1;     // h-index 0..63 — owns all 3 gates for this j
    const int q   = tid & 1;      // K-split half (= DPP pair lane)
    const int kh0 = q * 32;       // h-k slice [kh0, kh0+32)
    const int kx0 = q * 16;       // x-k slice [kx0, kx0+16)

    __shared__ v2f x_lds[T * D / 2];                 // 64 KB staged x row
    __shared__ __align__(16) float h_lds[2][H];      // double-buffered h
    __shared__ float last_lds[2 * H];

    // ---- per-lane weight slices in registers as native v2f (144 floats) ----
    v2f wr2[16], wz2[16], wn2[16], ur2[8], uz2[8], un2[8];
    {
        const v2f* pr = reinterpret_cast<const v2f*>(w_hh_f + (size_t)j * H + kh0);
        const v2f* pz = reinterpret_cast<const v2f*>(w_hh_f + (size_t)(H + j) * H + kh0);
        const v2f* pn = reinterpret_cast<const v2f*>(w_hh_f + (size_t)(2 * H + j) * H + kh0);
        #pragma unroll
        for (int m = 0; m < 16; ++m) { wr2[m] = pr[m]; wz2[m] = pz[m]; wn2[m] = pn[m]; }
        const v2f* qr = reinterpret_cast<const v2f*>(w_ih_f + (size_t)j * D + kx0);
        const v2f* qz = reinterpret_cast<const v2f*>(w_ih_f + (size_t)(H + j) * D + kx0);
        const v2f* qn = reinterpret_cast<const v2f*>(w_ih_f + (size_t)(2 * H + j) * D + kx0);
        #pragma unroll
        for (int m = 0; m < 8; ++m) { ur2[m] = qr[m]; uz2[m] = qz[m]; un2[m] = qn[m]; }
    }

    // biases: added exactly ONCE, AFTER the pair reduction
    const float pre_r  = b_ih_f[j]         + b_hh_f[j];
    const float pre_z  = b_ih_f[H + j]     + b_hh_f[H + j];
    const float pre_nx = b_ih_f[2 * H + j];
    const float pre_nh = b_hh_f[2 * H + j];

    // ---- stage x row into LDS (coalesced float4) ----
    {
        const float4* xg  = reinterpret_cast<const float4*>(x + (size_t)b * T * D);
        float4*       xl4 = reinterpret_cast<float4*>(x_lds);
        #pragma unroll 4
        for (int i = tid; i < T * D / 4; i += THREADS) xl4[i] = xg[i];
    }
    if (tid < H) h_lds[0][tid] = 0.0f;
    __syncthreads();

    // ---- x partials for t=0 (bias-free, unreduced) ----
    v2f axr = {0.f, 0.f}, axz = {0.f, 0.f}, axn = {0.f, 0.f};
    {
        const v2f* xt2 = x_lds + q * 8;   // t=0
        #pragma unroll
        for (int m = 0; m < 8; ++m) {
            v2f xv = xt2[m];
            pk2(axr, ur2[m], xv);
            pk2(axz, uz2[m], xv);
            pk2(axn, un2[m], xv);
        }
    }

    float hold = 0.0f;

    for (int t = 0; t < T; ++t) {
        const int cur = t & 1, nxt = cur ^ 1;

        // h slice: 32 floats as 16 v2f (contiguous -> ds_read_b128 bursts)
        v2f hh[16];
        {
            const v2f* hp = reinterpret_cast<const v2f*>(&h_lds[cur][kh0]);
            #pragma unroll
            for (int m = 0; m < 16; ++m) hh[m] = hp[m];
        }

        // h-dot seeded with this step's x partials: 48 pk2
        v2f pr = axr, pz = axz, nh = {0.f, 0.f};
        #pragma unroll
        for (int m = 0; m < 16; ++m) pk2(pr, wr2[m], hh[m]);
        #pragma unroll
        for (int m = 0; m < 16; ++m) pk2(pz, wz2[m], hh[m]);
        #pragma unroll
        for (int m = 0; m < 16; ++m) pk2(nh, wn2[m], hh[m]);
        const v2f axn_t = axn;   // n-gate x partial for THIS step

        // x partials for t+1 (independent of h — fills reduce/trans latency)
        {
            const int tn = (t + 1) & (T - 1);
            const v2f* xt2 = x_lds + tn * (D / 2) + q * 8;
            axr = {0.f, 0.f}; axz = {0.f, 0.f}; axn = {0.f, 0.f};
            #pragma unroll
            for (int m = 0; m < 8; ++m) {
                v2f xv = xt2[m];
                pk2(axr, ur2[m], xv);
                pk2(axz, uz2[m], xv);
                pk2(axn, un2[m], xv);
            }
        }

        // pair reduction: single DPP butterfly each, pure VALU
        const float vr  = pair_sum(pr.x + pr.y);
        const float vz  = pair_sum(pz.x + pz.y);
        const float vnh = pair_sum(nh.x + nh.y);
        const float vnx = pair_sum(axn_t.x + axn_t.y);

        const float r = sigm(vr + pre_r);
        const float z = sigm(vz + pre_z);
        const float n = tanh_fast(vnx + pre_nx + r * (vnh + pre_nh));
        const float hnew = n + z * (hold - n);   // (1-z)n + z*hold
        hold = hnew;
        if (q == 0) h_lds[nxt][j] = hnew;
        __syncthreads();   // single barrier per step, only 2 waves
    }

    // ---- epilogue ----
    const int wave = tid >> 6, lane = tid & 63;

    // forward final state (T even -> buffer 0)
    if (wave == 0) last_lds[lane] = h_lds[T & 1][lane];

    // backward direction: exactly ONE step from h0 = 0 on x[b][T-1][:]
    if (wave == 1) {
        const float* xT = reinterpret_cast<const float*>(x_lds) + (T - 1) * D;
        const int jj = lane;
        float xr = b_ih_b[jj];
        float xz = b_ih_b[H + jj];
        float xn = b_ih_b[2 * H + jj];
        #pragma unroll
        for (int k = 0; k < D; ++k) {
            const float xv = xT[k];
            xr = fmaf(w_ih_b[(size_t)jj * D + k],           xv, xr);
            xz = fmaf(w_ih_b[(size_t)(H + jj) * D + k],     xv, xz);
            xn = fmaf(w_ih_b[(size_t)(2 * H + jj) * D + k], xv, xn);
        }
        const float r = sigm(xr + b_hh_b[jj]);
        const float z = sigm(xz + b_hh_b[H + jj]);
        const float n = tanh_fast(xn + r * b_hh_b[2 * H + jj]);
        last_lds[H + jj] = (1.0f - z) * n;   // z*h0 = 0
    }
    __syncthreads();

    // head: h1 = leaky(fc1_w @ last + fc1_b); out = fc2_w @ h1 + fc2_b
    if (wave == 0) {
        float acc = fc1_b[lane];
        const float* w1 = fc1_w + (size_t)lane * (2 * H);
        #pragma unroll 8
        for (int c = 0; c < 2 * H; ++c) acc = fmaf(w1[c], last_lds[c], acc);
        acc = (acc >= 0.0f) ? acc : 0.2f * acc;
        float red = acc * fc2_w[lane];
        #pragma unroll
        for (int off = 32; off > 0; off >>= 1)
            red += __shfl_down(red, off);
        if (lane == 0) out[b] = red + fc2_b[0];
    }
}

extern "C" void kernel_launch(void* const* d_in, const int* in_sizes, int n_in,
                              void* d_out, int out_size, void* d_ws, size_t ws_size,
                              hipStream_t stream) {
    const float* x      = (const float*)d_in[0];
    const float* w_ih_f = (const float*)d_in[1];
    const float* w_hh_f = (const float*)d_in[2];
    const float* b_ih_f = (const float*)d_in[3];
    const float* b_hh_f = (const float*)d_in[4];
    const float* w_ih_b = (const float*)d_in[5];
    // d_in[6] = w_hh_b: unused (backward direction runs exactly one step from h0=0)
    const float* b_ih_b = (const float*)d_in[7];
    const float* b_hh_b = (const float*)d_in[8];
    const float* fc1_w  = (const float*)d_in[9];
    const float* fc1_b  = (const float*)d_in[10];
    const float* fc2_w  = (const float*)d_in[11];
    const float* fc2_b  = (const float*)d_in[12];
    float* out = (float*)d_out;

    gru_fused_kernel<<<BATCH, THREADS, 0, stream>>>(
        x, w_ih_f, w_hh_f, b_ih_f, b_hh_f,
        w_ih_b, b_ih_b, b_hh_b,
        fc1_w, fc1_b, fc2_w, fc2_b, out);
}

// Round 17
// 191.135 us; speedup vs baseline: 1.9216x; 1.0584x over previous
//
#include <hip/hip_runtime.h>

namespace {
constexpr int T = 512;
constexpr int BATCH = 512;
constexpr int D = 32;
constexpr int H = 64;
constexpr int THREADS = 128;  // 2 waves/row; lane pair (2j,2j+1) shares h-index j
}

typedef float v2f __attribute__((ext_vector_type(2)));

__device__ __forceinline__ float rcpf(float x) { return __builtin_amdgcn_rcpf(x); }
__device__ __forceinline__ float sigm(float x) { return rcpf(1.0f + __expf(-x)); }
__device__ __forceinline__ float tanh_fast(float x) {
    // 1 - 2/(e^{2x}+1); saturates via inf/0 at extremes
    return 1.0f - 2.0f * rcpf(__expf(2.0f * x) + 1.0f);
}

// packed fp32 FMA on native 64-bit vector registers: no operand repacking
__device__ __forceinline__ void pk2(v2f& acc, v2f w, v2f v) {
    asm("v_pk_fma_f32 %0, %1, %2, %0" : "+v"(acc) : "v"(w), "v"(v));
}

// sum across a lane pair (l, l^1) — single DPP quad_perm [1,0,3,2], pure VALU
__device__ __forceinline__ float pair_sum(float v) {
    int i = __builtin_bit_cast(int, v);
    float t = __builtin_bit_cast(float,
        __builtin_amdgcn_update_dpp(0, i, 0xB1, 0xF, 0xF, true));
    return v + t;
}

// LDS-only barrier: drains lgkm (h_lds ordering) but leaves vmcnt in flight —
// __syncthreads() would drain vmcnt(0) too, serializing any rematerialized
// global weight reloads (VGPR=132 < full residency) into every step.
__device__ __forceinline__ void lds_barrier() {
    asm volatile("s_waitcnt lgkmcnt(0)" ::: "memory");
    __builtin_amdgcn_s_barrier();
}

__global__ __launch_bounds__(THREADS, 1) void gru_fused_kernel(
    const float* __restrict__ x,
    const float* __restrict__ w_ih_f, const float* __restrict__ w_hh_f,
    const float* __restrict__ b_ih_f, const float* __restrict__ b_hh_f,
    const float* __restrict__ w_ih_b, const float* __restrict__ b_ih_b,
    const float* __restrict__ b_hh_b,
    const float* __restrict__ fc1_w, const float* __restrict__ fc1_b,
    const float* __restrict__ fc2_w, const float* __restrict__ fc2_b,
    float* __restrict__ out)
{
    const int b   = blockIdx.x;   // batch row
    const int tid = threadIdx.x;
    const int j   = tid >> 1;     // h-index 0..63 — owns all 3 gates for this j
    const int q   = tid & 1;      // K-split half (= DPP pair lane)
    const int kh0 = q * 32;       // h-k slice [kh0, kh0+32)
    const int kx0 = q * 16;       // x-k slice [kx0, kx0+16)

    __shared__ v2f x_lds[T * D / 2];                 // 64 KB staged x row
    __shared__ __align__(16) float h_lds[2][H];      // double-buffered h
    __shared__ float last_lds[2 * H];

    // ---- per-lane weight slices in registers as native v2f (144 floats) ----
    v2f wr2[16], wz2[16], wn2[16], ur2[8], uz2[8], un2[8];
    {
        const v2f* pr = reinterpret_cast<const v2f*>(w_hh_f + (size_t)j * H + kh0);
        const v2f* pz = reinterpret_cast<const v2f*>(w_hh_f + (size_t)(H + j) * H + kh0);
        const v2f* pn = reinterpret_cast<const v2f*>(w_hh_f + (size_t)(2 * H + j) * H + kh0);
        #pragma unroll
        for (int m = 0; m < 16; ++m) { wr2[m] = pr[m]; wz2[m] = pz[m]; wn2[m] = pn[m]; }
        const v2f* qr = reinterpret_cast<const v2f*>(w_ih_f + (size_t)j * D + kx0);
        const v2f* qz = reinterpret_cast<const v2f*>(w_ih_f + (size_t)(H + j) * D + kx0);
        const v2f* qn = reinterpret_cast<const v2f*>(w_ih_f + (size_t)(2 * H + j) * D + kx0);
        #pragma unroll
        for (int m = 0; m < 8; ++m) { ur2[m] = qr[m]; uz2[m] = qz[m]; un2[m] = qn[m]; }
    }

    // biases: added exactly ONCE, AFTER the pair reduction
    const float pre_r  = b_ih_f[j]         + b_hh_f[j];
    const float pre_z  = b_ih_f[H + j]     + b_hh_f[H + j];
    const float pre_nx = b_ih_f[2 * H + j];
    const float pre_nh = b_hh_f[2 * H + j];

    // ---- stage x row into LDS (coalesced float4) ----
    {
        const float4* xg  = reinterpret_cast<const float4*>(x + (size_t)b * T * D);
        float4*       xl4 = reinterpret_cast<float4*>(x_lds);
        #pragma unroll 4
        for (int i = tid; i < T * D / 4; i += THREADS) xl4[i] = xg[i];
    }
    if (tid < H) h_lds[0][tid] = 0.0f;
    __syncthreads();

    // ---- prologue: x-dot partials for t=0; raw x[1] into registers ----
    v2f axrA = {0.f,0.f}, axzA = {0.f,0.f}, axnA = {0.f,0.f};
    {
        const v2f* xt2 = x_lds + q * 8;   // t=0
        #pragma unroll
        for (int m = 0; m < 8; ++m) {
            v2f xv = xt2[m];
            pk2(axrA, ur2[m], xv); pk2(axzA, uz2[m], xv); pk2(axnA, un2[m], xv);
        }
    }
    v2f xvA[8];   // raw x[t+1] values (pipelined one step ahead)
    {
        const v2f* xt2 = x_lds + (D / 2) + q * 8;   // t=1
        #pragma unroll
        for (int m = 0; m < 8; ++m) xvA[m] = xt2[m];
    }
    v2f axrB, axzB, axnB;
    v2f xvB[8];

    float hold = 0.0f;

    // One step. Order engineered for the critical path:
    //  1. issue h-reads  2. issue raw x[T2] reads  3. x-dot(t+1) from
    //  ALREADY-LOADED regs (hides h-read latency)  4. h-dot  5. r-reduce +
    //  sigm FIRST (longest trans chain), other reduces under exp latency
    //  6. update, unconditional paired write (2-way same-addr = free)
    //  7. lgkm-only barrier.
    #define GRU_STEP(CUR, NXT, AXR,AXZ,AXN, XV, AXR2,AXZ2,AXN2, XV2, T2)       \
    {                                                                          \
        v2f hh[16];                                                            \
        {                                                                      \
            const v2f* hp = reinterpret_cast<const v2f*>(&h_lds[CUR][kh0]);    \
            _Pragma("unroll")                                                  \
            for (int m = 0; m < 16; ++m) hh[m] = hp[m];                        \
        }                                                                      \
        {                                                                      \
            const v2f* xt2 = x_lds + (size_t)((T2) & (T - 1)) * (D / 2) + q * 8;\
            _Pragma("unroll")                                                  \
            for (int m = 0; m < 8; ++m) XV2[m] = xt2[m];                       \
        }                                                                      \
        AXR2 = {0.f,0.f}; AXZ2 = {0.f,0.f}; AXN2 = {0.f,0.f};                  \
        _Pragma("unroll")                                                      \
        for (int m = 0; m < 8; ++m) {                                          \
            pk2(AXR2, ur2[m], XV[m]);                                          \
            pk2(AXZ2, uz2[m], XV[m]);                                          \
            pk2(AXN2, un2[m], XV[m]);                                          \
        }                                                                      \
        v2f pr = AXR, pz = AXZ, nh = {0.f,0.f};                                \
        _Pragma("unroll")                                                      \
        for (int m = 0; m < 16; ++m) pk2(pr, wr2[m], hh[m]);                   \
        _Pragma("unroll")                                                      \
        for (int m = 0; m < 16; ++m) pk2(pz, wz2[m], hh[m]);                   \
        _Pragma("unroll")                                                      \
        for (int m = 0; m < 16; ++m) pk2(nh, wn2[m], hh[m]);                   \
        const float vr = pair_sum(pr.x + pr.y);                                \
        const float r  = sigm(vr + pre_r);       /* longest chain first */     \
        const float vz  = pair_sum(pz.x + pz.y);                               \
        const float vnh = pair_sum(nh.x + nh.y);                               \
        const float vnx = pair_sum(AXN.x + AXN.y);                             \
        const float z  = sigm(vz + pre_z);                                     \
        const float n  = tanh_fast(vnx + pre_nx + r * (vnh + pre_nh));         \
        const float hnew = n + z * (hold - n);   /* (1-z)n + z*hold */         \
        hold = hnew;                                                           \
        h_lds[NXT][j] = hnew;   /* both pair lanes write same value */         \
        lds_barrier();                                                         \
    }

    for (int t = 0; t < T; t += 2) {
        GRU_STEP(0, 1, axrA, axzA, axnA, xvA, axrB, axzB, axnB, xvB, t + 2)
        GRU_STEP(1, 0, axrB, axzB, axnB, xvB, axrA, axzA, axnA, xvA, t + 3)
    }
    #undef GRU_STEP

    // ---- epilogue ----
    const int wave = tid >> 6, lane = tid & 63;

    // forward final state (T even -> buffer 0)
    if (wave == 0) last_lds[lane] = h_lds[T & 1][lane];

    // backward direction: exactly ONE step from h0 = 0 on x[b][T-1][:]
    if (wave == 1) {
        const float* xT = reinterpret_cast<const float*>(x_lds) + (T - 1) * D;
        const int jj = lane;
        float xr = b_ih_b[jj];
        float xz = b_ih_b[H + jj];
        float xn = b_ih_b[2 * H + jj];
        #pragma unroll
        for (int k = 0; k < D; ++k) {
            const float xv = xT[k];
            xr = fmaf(w_ih_b[(size_t)jj * D + k],           xv, xr);
            xz = fmaf(w_ih_b[(size_t)(H + jj) * D + k],     xv, xz);
            xn = fmaf(w_ih_b[(size_t)(2 * H + jj) * D + k], xv, xn);
        }
        const float r = sigm(xr + b_hh_b[jj]);
        const float z = sigm(xz + b_hh_b[H + jj]);
        const float n = tanh_fast(xn + r * b_hh_b[2 * H + jj]);
        last_lds[H + jj] = (1.0f - z) * n;   // z*h0 = 0
    }
    __syncthreads();

    // head: h1 = leaky(fc1_w @ last + fc1_b); out = fc2_w @ h1 + fc2_b
    if (wave == 0) {
        float acc = fc1_b[lane];
        const float* w1 = fc1_w + (size_t)lane * (2 * H);
        #pragma unroll 8
        for (int c = 0; c < 2 * H; ++c) acc = fmaf(w1[c], last_lds[c], acc);
        acc = (acc >= 0.0f) ? acc : 0.2f * acc;
        float red = acc * fc2_w[lane];
        #pragma unroll
        for (int off = 32; off > 0; off >>= 1)
            red += __shfl_down(red, off);
        if (lane == 0) out[b] = red + fc2_b[0];
    }
}

extern "C" void kernel_launch(void* const* d_in, const int* in_sizes, int n_in,
                              void* d_out, int out_size, void* d_ws, size_t ws_size,
                              hipStream_t stream) {
    const float* x      = (const float*)d_in[0];
    const float* w_ih_f = (const float*)d_in[1];
    const float* w_hh_f = (const float*)d_in[2];
    const float* b_ih_f = (const float*)d_in[3];
    const float* b_hh_f = (const float*)d_in[4];
    const float* w_ih_b = (const float*)d_in[5];
    // d_in[6] = w_hh_b: unused (backward direction runs exactly one step from h0=0)
    const float* b_ih_b = (const float*)d_in[7];
    const float* b_hh_b = (const float*)d_in[8];
    const float* fc1_w  = (const float*)d_in[9];
    const float* fc1_b  = (const float*)d_in[10];
    const float* fc2_w  = (const float*)d_in[11];
    const float* fc2_b  = (const float*)d_in[12];
    float* out = (float*)d_out;

    gru_fused_kernel<<<BATCH, THREADS, 0, stream>>>(
        x, w_ih_f, w_hh_f, b_ih_f, b_hh_f,
        w_ih_b, b_ih_b, b_hh_b,
        fc1_w, fc1_b, fc2_w, fc2_b, out);
}

// Round 18
// 177.678 us; speedup vs baseline: 2.0671x; 1.0757x over previous
//
#include <hip/hip_runtime.h>

namespace {
constexpr int T = 512;
constexpr int BATCH = 512;
constexpr int D = 32;
constexpr int H = 64;
constexpr int THREADS = 128;  // 2 waves/row; lane pair (2j,2j+1) shares h-index j
}

typedef float v2f __attribute__((ext_vector_type(2)));

__device__ __forceinline__ float rcpf(float x) { return __builtin_amdgcn_rcpf(x); }
// pre-scaled transcendentals: inputs already carry log2e / 2*log2e factors,
// so these are raw v_exp_f32 (2^x) + v_rcp with NO scaling muls on the chain.
__device__ __forceinline__ float sigm_pre(float y) {   // sigmoid(y/log2e)
    return rcpf(1.0f + __builtin_amdgcn_exp2f(-y));
}
__device__ __forceinline__ float tanh_pre(float y) {   // tanh(y/(2*log2e))
    return 1.0f - 2.0f * rcpf(__builtin_amdgcn_exp2f(y) + 1.0f);
}

// packed fp32 FMA on native 64-bit vector registers: no operand repacking
__device__ __forceinline__ void pk2(v2f& acc, v2f w, v2f v) {
    asm("v_pk_fma_f32 %0, %1, %2, %0" : "+v"(acc) : "v"(w), "v"(v));
}

// sum across a lane pair (l, l^1) — single DPP quad_perm [1,0,3,2], pure VALU
__device__ __forceinline__ float pair_sum(float v) {
    int i = __builtin_bit_cast(int, v);
    float t = __builtin_bit_cast(float,
        __builtin_amdgcn_update_dpp(0, i, 0xB1, 0xF, 0xF, true));
    return v + t;
}

// LDS-only barrier: drains lgkm (h_lds ordering) but leaves vmcnt in flight.
__device__ __forceinline__ void lds_barrier() {
    asm volatile("s_waitcnt lgkmcnt(0)" ::: "memory");
    __builtin_amdgcn_s_barrier();
}

__global__ __launch_bounds__(THREADS, 1) void gru_fused_kernel(
    const float* __restrict__ x,
    const float* __restrict__ w_ih_f, const float* __restrict__ w_hh_f,
    const float* __restrict__ b_ih_f, const float* __restrict__ b_hh_f,
    const float* __restrict__ w_ih_b, const float* __restrict__ b_ih_b,
    const float* __restrict__ b_hh_b,
    const float* __restrict__ fc1_w, const float* __restrict__ fc1_b,
    const float* __restrict__ fc2_w, const float* __restrict__ fc2_b,
    float* __restrict__ out)
{
    const int b   = blockIdx.x;   // batch row
    const int tid = threadIdx.x;
    const int j   = tid >> 1;     // h-index 0..63 — owns all 3 gates for this j
    const int q   = tid & 1;      // K-split half (= DPP pair lane)
    const int kh0 = q * 32;       // h-k slice [kh0, kh0+32)
    const int kx0 = q * 16;       // x-k slice [kx0, kx0+16)

    constexpr float LOG2E  = 1.4426950408889634f;
    constexpr float LOG2E2 = 2.0f * LOG2E;

    __shared__ v2f x_lds[T * D / 2];                 // 64 KB staged x row
    __shared__ __align__(16) float h_lds[2][H];      // double-buffered h
    __shared__ float last_lds[2 * H];

    // ---- per-lane weight slices in registers, PRE-SCALED for exp2 trans ----
    // r/z rows ×log2e (sigmoid), n rows ×2*log2e (tanh via exp2(2x*log2e)).
    v2f wr2[16], wz2[16], wn2[16], ur2[8], uz2[8], un2[8];
    {
        const v2f* pr = reinterpret_cast<const v2f*>(w_hh_f + (size_t)j * H + kh0);
        const v2f* pz = reinterpret_cast<const v2f*>(w_hh_f + (size_t)(H + j) * H + kh0);
        const v2f* pn = reinterpret_cast<const v2f*>(w_hh_f + (size_t)(2 * H + j) * H + kh0);
        #pragma unroll
        for (int m = 0; m < 16; ++m) {
            wr2[m] = pr[m] * LOG2E;
            wz2[m] = pz[m] * LOG2E;
            wn2[m] = pn[m] * LOG2E2;
        }
        const v2f* qr = reinterpret_cast<const v2f*>(w_ih_f + (size_t)j * D + kx0);
        const v2f* qz = reinterpret_cast<const v2f*>(w_ih_f + (size_t)(H + j) * D + kx0);
        const v2f* qn = reinterpret_cast<const v2f*>(w_ih_f + (size_t)(2 * H + j) * D + kx0);
        #pragma unroll
        for (int m = 0; m < 8; ++m) {
            ur2[m] = qr[m] * LOG2E;
            uz2[m] = qz[m] * LOG2E;
            un2[m] = qn[m] * LOG2E2;
        }
    }

    // scaled HALF-biases: seeded into BOTH pair lanes' accumulators; the
    // pair_sum doubles them back to 1x. Removes all bias adds from the CP.
    const float hpre_r  = 0.5f * LOG2E  * (b_ih_f[j]         + b_hh_f[j]);
    const float hpre_z  = 0.5f * LOG2E  * (b_ih_f[H + j]     + b_hh_f[H + j]);
    const float hpre_nx = LOG2E * b_ih_f[2 * H + j];   // 0.5 * 2log2e
    const float hpre_nh = LOG2E * b_hh_f[2 * H + j];

    // ---- stage x row into LDS (coalesced float4) ----
    {
        const float4* xg  = reinterpret_cast<const float4*>(x + (size_t)b * T * D);
        float4*       xl4 = reinterpret_cast<float4*>(x_lds);
        #pragma unroll 4
        for (int i = tid; i < T * D / 4; i += THREADS) xl4[i] = xg[i];
    }
    if (tid < H) h_lds[0][tid] = 0.0f;
    __syncthreads();

    // ---- prologue: x partials for t=0 (bias-seeded); raw x[1]; vnx reduced ----
    v2f axrA = {hpre_r, 0.f}, axzA = {hpre_z, 0.f};
    float vnxA;
    {
        const v2f* xt2 = x_lds + q * 8;   // t=0
        v2f axn = {hpre_nx, 0.f};
        #pragma unroll
        for (int m = 0; m < 8; ++m) {
            v2f xv = xt2[m];
            pk2(axrA, ur2[m], xv); pk2(axzA, uz2[m], xv); pk2(axn, un2[m], xv);
        }
        vnxA = pair_sum(axn.x + axn.y);
    }
    v2f xvA[8];   // raw x[t+1] values (pipelined one step ahead)
    {
        const v2f* xt2 = x_lds + (D / 2) + q * 8;   // t=1
        #pragma unroll
        for (int m = 0; m < 8; ++m) xvA[m] = xt2[m];
    }
    v2f axrB, axzB;
    float vnxB;
    v2f xvB[8];

    float hold = 0.0f;

    // Step order: issue h-reads -> issue raw x[T2] reads -> shadow phase
    // (t+1 x-dot + its n-reduce, from already-loaded regs; hides h latency)
    // -> h-dot -> r-reduce + sigm FIRST -> z/nh reduces under exp latency
    // -> n (tanh chained on r) -> fused update -> paired write -> lgkm barrier.
    #define GRU_STEP(CUR, NXT, AXR,AXZ, VNX, XV, AXR2,AXZ2, VNX2, XV2, T2)     \
    {                                                                          \
        v2f hh[16];                                                            \
        {                                                                      \
            const v2f* hp = reinterpret_cast<const v2f*>(&h_lds[CUR][kh0]);    \
            _Pragma("unroll")                                                  \
            for (int m = 0; m < 16; ++m) hh[m] = hp[m];                        \
        }                                                                      \
        {                                                                      \
            const v2f* xt2 = x_lds + (size_t)((T2) & (T - 1)) * (D / 2) + q * 8;\
            _Pragma("unroll")                                                  \
            for (int m = 0; m < 8; ++m) XV2[m] = xt2[m];                       \
        }                                                                      \
        AXR2 = {hpre_r, 0.f}; AXZ2 = {hpre_z, 0.f};                            \
        {                                                                      \
            v2f axn2 = {hpre_nx, 0.f};                                         \
            _Pragma("unroll")                                                  \
            for (int m = 0; m < 8; ++m) {                                      \
                pk2(AXR2, ur2[m], XV[m]);                                      \
                pk2(AXZ2, uz2[m], XV[m]);                                      \
                pk2(axn2, un2[m], XV[m]);                                      \
            }                                                                  \
            VNX2 = pair_sum(axn2.x + axn2.y);                                  \
        }                                                                      \
        v2f pr = AXR, pz = AXZ, nh = {hpre_nh, 0.f};                           \
        _Pragma("unroll")                                                      \
        for (int m = 0; m < 16; ++m) pk2(pr, wr2[m], hh[m]);                   \
        _Pragma("unroll")                                                      \
        for (int m = 0; m < 16; ++m) pk2(pz, wz2[m], hh[m]);                   \
        _Pragma("unroll")                                                      \
        for (int m = 0; m < 16; ++m) pk2(nh, wn2[m], hh[m]);                   \
        const float vr = pair_sum(pr.x + pr.y);                                \
        const float r  = sigm_pre(vr);           /* longest chain first */     \
        const float vz  = pair_sum(pz.x + pz.y);                               \
        const float vnh = pair_sum(nh.x + nh.y);                               \
        const float z  = sigm_pre(vz);                                         \
        const float n  = tanh_pre(fmaf(r, vnh, VNX));                          \
        const float hnew = fmaf(z, hold - n, n); /* (1-z)n + z*hold */         \
        hold = hnew;                                                           \
        h_lds[NXT][j] = hnew;   /* both pair lanes write same value */         \
        lds_barrier();                                                         \
    }

    for (int t = 0; t < T; t += 2) {
        GRU_STEP(0, 1, axrA, axzA, vnxA, xvA, axrB, axzB, vnxB, xvB, t + 2)
        GRU_STEP(1, 0, axrB, axzB, vnxB, xvB, axrA, axzA, vnxA, xvA, t + 3)
    }
    #undef GRU_STEP

    // ---- epilogue ----
    const int wave = tid >> 6, lane = tid & 63;

    // forward final state (T even -> buffer 0)
    if (wave == 0) last_lds[lane] = h_lds[T & 1][lane];

    // backward direction: exactly ONE step from h0 = 0 on x[b][T-1][:]
    // (uses original unscaled weights/biases from global)
    if (wave == 1) {
        const float* xT = reinterpret_cast<const float*>(x_lds) + (T - 1) * D;
        const int jj = lane;
        float xr = b_ih_b[jj];
        float xz = b_ih_b[H + jj];
        float xn = b_ih_b[2 * H + jj];
        #pragma unroll
        for (int k = 0; k < D; ++k) {
            const float xv = xT[k];
            xr = fmaf(w_ih_b[(size_t)jj * D + k],           xv, xr);
            xz = fmaf(w_ih_b[(size_t)(H + jj) * D + k],     xv, xz);
            xn = fmaf(w_ih_b[(size_t)(2 * H + jj) * D + k], xv, xn);
        }
        const float r = rcpf(1.0f + __expf(-(xr + b_hh_b[jj])));
        const float z = rcpf(1.0f + __expf(-(xz + b_hh_b[H + jj])));
        const float u = xn + r * b_hh_b[2 * H + jj];
        const float n = 1.0f - 2.0f * rcpf(__expf(2.0f * u) + 1.0f);
        last_lds[H + jj] = (1.0f - z) * n;   // z*h0 = 0
    }
    __syncthreads();

    // head: h1 = leaky(fc1_w @ last + fc1_b); out = fc2_w @ h1 + fc2_b
    if (wave == 0) {
        float acc = fc1_b[lane];
        const float* w1 = fc1_w + (size_t)lane * (2 * H);
        #pragma unroll 8
        for (int c = 0; c < 2 * H; ++c) acc = fmaf(w1[c], last_lds[c], acc);
        acc = (acc >= 0.0f) ? acc : 0.2f * acc;
        float red = acc * fc2_w[lane];
        #pragma unroll
        for (int off = 32; off > 0; off >>= 1)
            red += __shfl_down(red, off);
        if (lane == 0) out[b] = red + fc2_b[0];
    }
}

extern "C" void kernel_launch(void* const* d_in, const int* in_sizes, int n_in,
                              void* d_out, int out_size, void* d_ws, size_t ws_size,
                              hipStream_t stream) {
    const float* x      = (const float*)d_in[0];
    const float* w_ih_f = (const float*)d_in[1];
    const float* w_hh_f = (const float*)d_in[2];
    const float* b_ih_f = (const float*)d_in[3];
    const float* b_hh_f = (const float*)d_in[4];
    const float* w_ih_b = (const float*)d_in[5];
    // d_in[6] = w_hh_b: unused (backward direction runs exactly one step from h0=0)
    const float* b_ih_b = (const float*)d_in[7];
    const float* b_hh_b = (const float*)d_in[8];
    const float* fc1_w  = (const float*)d_in[9];
    const float* fc1_b  = (const float*)d_in[10];
    const float* fc2_w  = (const float*)d_in[11];
    const float* fc2_b  = (const float*)d_in[12];
    float* out = (float*)d_out;

    gru_fused_kernel<<<BATCH, THREADS, 0, stream>>>(
        x, w_ih_f, w_hh_f, b_ih_f, b_hh_f,
        w_ih_b, b_ih_b, b_hh_b,
        fc1_w, fc1_b, fc2_w, fc2_b, out);
}

// Round 19
// 176.668 us; speedup vs baseline: 2.0789x; 1.0057x over previous
//
#include <hip/hip_runtime.h>

namespace {
constexpr int T = 512;
constexpr int BATCH = 512;
constexpr int D = 32;
constexpr int H = 64;
constexpr int THREADS = 128;  // 2 waves/row; lane pair (2j,2j+1) shares h-index j
}

typedef float v2f __attribute__((ext_vector_type(2)));
typedef float v4f __attribute__((ext_vector_type(4)));

__device__ __forceinline__ float rcpf(float x) { return __builtin_amdgcn_rcpf(x); }
// pre-scaled transcendentals: inputs already carry log2e / 2*log2e factors.
__device__ __forceinline__ float sigm_pre(float y) {   // sigmoid(y/log2e)
    return rcpf(1.0f + __builtin_amdgcn_exp2f(-y));
}
__device__ __forceinline__ float tanh_pre(float y) {   // tanh(y/(2*log2e))
    return 1.0f - 2.0f * rcpf(__builtin_amdgcn_exp2f(y) + 1.0f);
}

// packed fp32 FMA on native 64-bit vector registers: no operand repacking
__device__ __forceinline__ void pk2(v2f& acc, v2f w, v2f v) {
    asm("v_pk_fma_f32 %0, %1, %2, %0" : "+v"(acc) : "v"(w), "v"(v));
}

// sum across a lane pair (l, l^1) — single DPP quad_perm [1,0,3,2], pure VALU
__device__ __forceinline__ float pair_sum(float v) {
    int i = __builtin_bit_cast(int, v);
    float t = __builtin_bit_cast(float,
        __builtin_amdgcn_update_dpp(0, i, 0xB1, 0xF, 0xF, true));
    return v + t;
}

// LDS-only barrier: drains lgkm (h_lds ordering) but leaves vmcnt in flight.
__device__ __forceinline__ void lds_barrier() {
    asm volatile("s_waitcnt lgkmcnt(0)" ::: "memory");
    __builtin_amdgcn_s_barrier();
}

__global__ __launch_bounds__(THREADS, 1) void gru_fused_kernel(
    const float* __restrict__ x,
    const float* __restrict__ w_ih_f, const float* __restrict__ w_hh_f,
    const float* __restrict__ b_ih_f, const float* __restrict__ b_hh_f,
    const float* __restrict__ w_ih_b, const float* __restrict__ b_ih_b,
    const float* __restrict__ b_hh_b,
    const float* __restrict__ fc1_w, const float* __restrict__ fc1_b,
    const float* __restrict__ fc2_w, const float* __restrict__ fc2_b,
    float* __restrict__ out)
{
    const int b   = blockIdx.x;   // batch row
    const int tid = threadIdx.x;
    const int j   = tid >> 1;     // h-index 0..63 — owns all 3 gates for this j
    const int q   = tid & 1;      // K-split half (= DPP pair lane)
    const int kh0 = q * 32;       // h-k slice [kh0, kh0+32)
    const int kx0 = q * 16;       // x-k slice [kx0, kx0+16)

    constexpr float LOG2E  = 1.4426950408889634f;
    constexpr float LOG2E2 = 2.0f * LOG2E;

    __shared__ v4f x_lds[T * D / 4];                 // 64 KB staged x row
    __shared__ __align__(16) float h_lds[2][H];      // double-buffered h
    __shared__ float last_lds[2 * H];

    // ---- per-lane weight slices in registers, PRE-SCALED for exp2 trans ----
    v2f wr2[16], wz2[16], wn2[16], ur2[8], uz2[8], un2[8];
    {
        const v2f* pr = reinterpret_cast<const v2f*>(w_hh_f + (size_t)j * H + kh0);
        const v2f* pz = reinterpret_cast<const v2f*>(w_hh_f + (size_t)(H + j) * H + kh0);
        const v2f* pn = reinterpret_cast<const v2f*>(w_hh_f + (size_t)(2 * H + j) * H + kh0);
        #pragma unroll
        for (int m = 0; m < 16; ++m) {
            wr2[m] = pr[m] * LOG2E;
            wz2[m] = pz[m] * LOG2E;
            wn2[m] = pn[m] * LOG2E2;
        }
        const v2f* qr = reinterpret_cast<const v2f*>(w_ih_f + (size_t)j * D + kx0);
        const v2f* qz = reinterpret_cast<const v2f*>(w_ih_f + (size_t)(H + j) * D + kx0);
        const v2f* qn = reinterpret_cast<const v2f*>(w_ih_f + (size_t)(2 * H + j) * D + kx0);
        #pragma unroll
        for (int m = 0; m < 8; ++m) {
            ur2[m] = qr[m] * LOG2E;
            uz2[m] = qz[m] * LOG2E;
            un2[m] = qn[m] * LOG2E2;
        }
    }

    // scaled HALF-biases: seeded into BOTH pair lanes; pair_sum restores 1x.
    const float hpre_r  = 0.5f * LOG2E  * (b_ih_f[j]         + b_hh_f[j]);
    const float hpre_z  = 0.5f * LOG2E  * (b_ih_f[H + j]     + b_hh_f[H + j]);
    const float hpre_nx = LOG2E * b_ih_f[2 * H + j];   // 0.5 * 2log2e
    const float hpre_nh = LOG2E * b_hh_f[2 * H + j];

    // ---- stage x row into LDS (coalesced b128) ----
    {
        const v4f* xg = reinterpret_cast<const v4f*>(x + (size_t)b * T * D);
        #pragma unroll 4
        for (int i = tid; i < T * D / 4; i += THREADS) x_lds[i] = xg[i];
    }
    if (tid < H) h_lds[0][tid] = 0.0f;
    __syncthreads();

    // ---- prologue: x partials for t=0 (bias-seeded); raw x[1]; vnx reduced ----
    v2f axrA = {hpre_r, 0.f}, axzA = {hpre_z, 0.f};
    float vnxA;
    {
        const v4f* xt4 = x_lds + q * 4;   // t=0
        v2f axn = {hpre_nx, 0.f};
        #pragma unroll
        for (int m = 0; m < 4; ++m) {
            v4f xq = xt4[m];
            v2f lo = __builtin_shufflevector(xq, xq, 0, 1);
            v2f hi = __builtin_shufflevector(xq, xq, 2, 3);
            pk2(axrA, ur2[2*m], lo); pk2(axrA, ur2[2*m+1], hi);
            pk2(axzA, uz2[2*m], lo); pk2(axzA, uz2[2*m+1], hi);
            pk2(axn,  un2[2*m], lo); pk2(axn,  un2[2*m+1], hi);
        }
        vnxA = pair_sum(axn.x + axn.y);
    }
    v4f xvA[4];   // raw x[t+1] values (pipelined one step ahead, b128 reads)
    {
        const v4f* xt4 = x_lds + (D / 4) + q * 4;   // t=1
        #pragma unroll
        for (int m = 0; m < 4; ++m) xvA[m] = xt4[m];
    }
    v2f axrB, axzB;
    float vnxB;
    v4f xvB[4];

    float hold = 0.0f;

    // Step order: issue h b128 reads -> issue raw x[T2] b128 reads -> shadow
    // phase (t+1 x-dot + its n-reduce from already-loaded regs; hides h
    // latency) -> h-dot -> r-reduce + sigm FIRST -> z/nh reduces under exp
    // latency -> n (tanh chained on r) -> fused update -> paired write ->
    // lgkm-only barrier (vmcnt loads stay in flight).
    #define GRU_STEP(CUR, NXT, AXR,AXZ, VNX, XV, AXR2,AXZ2, VNX2, XV2, T2)     \
    {                                                                          \
        v4f hh4[4];                                                            \
        {                                                                      \
            const v4f* hp = reinterpret_cast<const v4f*>(&h_lds[CUR][kh0]);    \
            _Pragma("unroll")                                                  \
            for (int m = 0; m < 4; ++m) hh4[m] = hp[m];                        \
        }                                                                      \
        {                                                                      \
            const v4f* xt4 = x_lds + (size_t)((T2) & (T - 1)) * (D / 4) + q * 4;\
            _Pragma("unroll")                                                  \
            for (int m = 0; m < 4; ++m) XV2[m] = xt4[m];                       \
        }                                                                      \
        AXR2 = {hpre_r, 0.f}; AXZ2 = {hpre_z, 0.f};                            \
        {                                                                      \
            v2f axn2 = {hpre_nx, 0.f};                                         \
            _Pragma("unroll")                                                  \
            for (int m = 0; m < 4; ++m) {                                      \
                v2f lo = __builtin_shufflevector(XV[m], XV[m], 0, 1);          \
                v2f hi = __builtin_shufflevector(XV[m], XV[m], 2, 3);          \
                pk2(AXR2, ur2[2*m], lo); pk2(AXR2, ur2[2*m+1], hi);            \
                pk2(AXZ2, uz2[2*m], lo); pk2(AXZ2, uz2[2*m+1], hi);            \
                pk2(axn2, un2[2*m], lo); pk2(axn2, un2[2*m+1], hi);            \
            }                                                                  \
            VNX2 = pair_sum(axn2.x + axn2.y);                                  \
        }                                                                      \
        v2f pr = AXR, pz = AXZ, nh = {hpre_nh, 0.f};                           \
        _Pragma("unroll")                                                      \
        for (int m = 0; m < 4; ++m) {                                          \
            v2f lo = __builtin_shufflevector(hh4[m], hh4[m], 0, 1);            \
            v2f hi = __builtin_shufflevector(hh4[m], hh4[m], 2, 3);            \
            pk2(pr, wr2[2*m], lo); pk2(pr, wr2[2*m+1], hi);                    \
            pk2(pz, wz2[2*m], lo); pk2(pz, wz2[2*m+1], hi);                    \
            pk2(nh, wn2[2*m], lo); pk2(nh, wn2[2*m+1], hi);                    \
        }                                                                      \
        _Pragma("unroll")                                                      \
        for (int m = 4; m < 8; ++m) {                                          \
            v2f lo = __builtin_shufflevector(hh4[m-4], hh4[m-4], 0, 1);        \
            (void)lo;                                                          \
        }                                                                      \
        /* second half of K-slice: wr2[8..15] against hh4 re-read — NO:    */  \
        /* kh0 slice is 32 floats = 8 v4f; fix: hh4 must be [8].           */  \
        const float vr = pair_sum(pr.x + pr.y);                                \
        const float r  = sigm_pre(vr);                                         \
        const float vz  = pair_sum(pz.x + pz.y);                               \
        const float vnh = pair_sum(nh.x + nh.y);                               \
        const float z  = sigm_pre(vz);                                         \
        const float n  = tanh_pre(fmaf(r, vnh, VNX));                          \
        const float hnew = fmaf(z, hold - n, n);                               \
        hold = hnew;                                                           \
        h_lds[NXT][j] = hnew;                                                  \
        lds_barrier();                                                         \
    }
    // (macro above intentionally unused — see corrected step below)
    #undef GRU_STEP

    // CORRECTED step: the 32-float h slice is 8 v4f, not 4.
    #define GRU_STEP(CUR, NXT, AXR,AXZ, VNX, XV, AXR2,AXZ2, VNX2, XV2, T2)     \
    {                                                                          \
        v4f hh4[8];                                                            \
        {                                                                      \
            const v4f* hp = reinterpret_cast<const v4f*>(&h_lds[CUR][kh0]);    \
            _Pragma("unroll")                                                  \
            for (int m = 0; m < 8; ++m) hh4[m] = hp[m];                        \
        }                                                                      \
        {                                                                      \
            const v4f* xt4 = x_lds + (size_t)((T2) & (T - 1)) * (D / 4) + q * 4;\
            _Pragma("unroll")                                                  \
            for (int m = 0; m < 4; ++m) XV2[m] = xt4[m];                       \
        }                                                                      \
        AXR2 = {hpre_r, 0.f}; AXZ2 = {hpre_z, 0.f};                            \
        {                                                                      \
            v2f axn2 = {hpre_nx, 0.f};                                         \
            _Pragma("unroll")                                                  \
            for (int m = 0; m < 4; ++m) {                                      \
                v2f lo = __builtin_shufflevector(XV[m], XV[m], 0, 1);          \
                v2f hi = __builtin_shufflevector(XV[m], XV[m], 2, 3);          \
                pk2(AXR2, ur2[2*m], lo); pk2(AXR2, ur2[2*m+1], hi);            \
                pk2(AXZ2, uz2[2*m], lo); pk2(AXZ2, uz2[2*m+1], hi);            \
                pk2(axn2, un2[2*m], lo); pk2(axn2, un2[2*m+1], hi);            \
            }                                                                  \
            VNX2 = pair_sum(axn2.x + axn2.y);                                  \
        }                                                                      \
        v2f pr = AXR, pz = AXZ, nh = {hpre_nh, 0.f};                           \
        _Pragma("unroll")                                                      \
        for (int m = 0; m < 8; ++m) {                                          \
            v2f lo = __builtin_shufflevector(hh4[m], hh4[m], 0, 1);            \
            v2f hi = __builtin_shufflevector(hh4[m], hh4[m], 2, 3);            \
            pk2(pr, wr2[2*m], lo); pk2(pr, wr2[2*m+1], hi);                    \
            pk2(pz, wz2[2*m], lo); pk2(pz, wz2[2*m+1], hi);                    \
            pk2(nh, wn2[2*m], lo); pk2(nh, wn2[2*m+1], hi);                    \
        }                                                                      \
        const float vr = pair_sum(pr.x + pr.y);                                \
        const float r  = sigm_pre(vr);           /* longest chain first */     \
        const float vz  = pair_sum(pz.x + pz.y);                               \
        const float vnh = pair_sum(nh.x + nh.y);                               \
        const float z  = sigm_pre(vz);                                         \
        const float n  = tanh_pre(fmaf(r, vnh, VNX));                          \
        const float hnew = fmaf(z, hold - n, n); /* (1-z)n + z*hold */         \
        hold = hnew;                                                           \
        h_lds[NXT][j] = hnew;   /* both pair lanes write same value */         \
        lds_barrier();                                                         \
    }

    for (int t = 0; t < T; t += 2) {
        GRU_STEP(0, 1, axrA, axzA, vnxA, xvA, axrB, axzB, vnxB, xvB, t + 2)
        GRU_STEP(1, 0, axrB, axzB, vnxB, xvB, axrA, axzA, vnxA, xvA, t + 3)
    }
    #undef GRU_STEP

    // ---- epilogue ----
    const int wave = tid >> 6, lane = tid & 63;

    // forward final state (T even -> buffer 0)
    if (wave == 0) last_lds[lane] = h_lds[T & 1][lane];

    // backward direction: exactly ONE step from h0 = 0 on x[b][T-1][:]
    if (wave == 1) {
        const float* xT = reinterpret_cast<const float*>(x_lds) + (T - 1) * D;
        const int jj = lane;
        float xr = b_ih_b[jj];
        float xz = b_ih_b[H + jj];
        float xn = b_ih_b[2 * H + jj];
        #pragma unroll
        for (int k = 0; k < D; ++k) {
            const float xv = xT[k];
            xr = fmaf(w_ih_b[(size_t)jj * D + k],           xv, xr);
            xz = fmaf(w_ih_b[(size_t)(H + jj) * D + k],     xv, xz);
            xn = fmaf(w_ih_b[(size_t)(2 * H + jj) * D + k], xv, xn);
        }
        const float r = rcpf(1.0f + __expf(-(xr + b_hh_b[jj])));
        const float z = rcpf(1.0f + __expf(-(xz + b_hh_b[H + jj])));
        const float u = xn + r * b_hh_b[2 * H + jj];
        const float n = 1.0f - 2.0f * rcpf(__expf(2.0f * u) + 1.0f);
        last_lds[H + jj] = (1.0f - z) * n;   // z*h0 = 0
    }
    __syncthreads();

    // head: h1 = leaky(fc1_w @ last + fc1_b); out = fc2_w @ h1 + fc2_b
    if (wave == 0) {
        float acc = fc1_b[lane];
        const float* w1 = fc1_w + (size_t)lane * (2 * H);
        #pragma unroll 8
        for (int c = 0; c < 2 * H; ++c) acc = fmaf(w1[c], last_lds[c], acc);
        acc = (acc >= 0.0f) ? acc : 0.2f * acc;
        float red = acc * fc2_w[lane];
        #pragma unroll
        for (int off = 32; off > 0; off >>= 1)
            red += __shfl_down(red, off);
        if (lane == 0) out[b] = red + fc2_b[0];
    }
}

extern "C" void kernel_launch(void* const* d_in, const int* in_sizes, int n_in,
                              void* d_out, int out_size, void* d_ws, size_t ws_size,
                              hipStream_t stream) {
    const float* x      = (const float*)d_in[0];
    const float* w_ih_f = (const float*)d_in[1];
    const float* w_hh_f = (const float*)d_in[2];
    const float* b_ih_f = (const float*)d_in[3];
    const float* b_hh_f = (const float*)d_in[4];
    const float* w_ih_b = (const float*)d_in[5];
    // d_in[6] = w_hh_b: unused (backward direction runs exactly one step from h0=0)
    const float* b_ih_b = (const float*)d_in[7];
    const float* b_hh_b = (const float*)d_in[8];
    const float* fc1_w  = (const float*)d_in[9];
    const float* fc1_b  = (const float*)d_in[10];
    const float* fc2_w  = (const float*)d_in[11];
    const float* fc2_b  = (const float*)d_in[12];
    float* out = (float*)d_out;

    gru_fused_kernel<<<BATCH, THREADS, 0, stream>>>(
        x, w_ih_f, w_hh_f, b_ih_f, b_hh_f,
        w_ih_b, b_ih_b, b_hh_b,
        fc1_w, fc1_b, fc2_w, fc2_b, out);
}